// Round 6
// baseline (146.342 us; speedup 1.0000x reference)
//
#include <hip/hip_runtime.h>
#include <hip/hip_bf16.h>
#include <math.h>

using short8 = __attribute__((ext_vector_type(8))) short;
using f32x4  = __attribute__((ext_vector_type(4))) float;

constexpr int S_LEN  = 256;
constexpr int T      = 2560;
constexpr int D_IN   = 512;
constexpr int DK     = 64;
constexpr int B_N    = 2;
constexpr int SS     = 16;     // split-K chunks for PV (T/SS = 160 per chunk)

__device__ __forceinline__ float wave_reduce_sum(float v) {
#pragma unroll
    for (int off = 32; off > 0; off >>= 1) v += __shfl_down(v, off);
    return v;
}

// ---------------------------------------------------------------------------
// LN: one row per block; writes xn as split bf16 (hi+lo), row-major 5120x512.
// ---------------------------------------------------------------------------
__global__ __launch_bounds__(256) void ln_kernel(
    const float* __restrict__ x,
    const float* __restrict__ g_m,  const float* __restrict__ b_m,
    const float* __restrict__ g_s,  const float* __restrict__ b_s,
    const float* __restrict__ g_e,  const float* __restrict__ b_e,
    __hip_bfloat16* __restrict__ xnh, __hip_bfloat16* __restrict__ xnl)
{
    const int tid = threadIdx.x;
    const int row = blockIdx.x;
    const int t   = row % T;

    __shared__ float red[4];

    const float *gv, *bv;
    if (t < S_LEN)          { gv = g_s; bv = b_s; }
    else if (t < T - S_LEN) { gv = g_m; bv = b_m; }
    else                    { gv = g_e; bv = b_e; }

    const float* xr = x + (size_t)row * D_IN;
    float a0 = xr[tid], a1 = xr[tid + 256];
    float s = wave_reduce_sum(a0 + a1);
    if ((tid & 63) == 0) red[tid >> 6] = s;
    __syncthreads();
    float mean = (red[0] + red[1] + red[2] + red[3]) * (1.0f / D_IN);
    float d0 = a0 - mean, d1 = a1 - mean;
    float sq = wave_reduce_sum(d0 * d0 + d1 * d1);
    __syncthreads();
    if ((tid & 63) == 0) red[tid >> 6] = sq;
    __syncthreads();
    float var = (red[0] + red[1] + red[2] + red[3]) * (1.0f / D_IN);
    float inv = rsqrtf(var + 1e-5f);

    float v0 = d0 * inv * gv[tid]       + bv[tid];
    float v1 = d1 * inv * gv[tid + 256] + bv[tid + 256];
    __hip_bfloat16 h0 = __float2bfloat16(v0);
    __hip_bfloat16 h1 = __float2bfloat16(v1);
    xnh[(size_t)row * D_IN + tid]       = h0;
    xnh[(size_t)row * D_IN + tid + 256] = h1;
    xnl[(size_t)row * D_IN + tid]       = __float2bfloat16(v0 - __bfloat162float(h0));
    xnl[(size_t)row * D_IN + tid + 256] = __float2bfloat16(v1 - __bfloat162float(h1));
}

// ---------------------------------------------------------------------------
// prep: 9 weight mats (512x64) -> WT[9][64][512] split bf16
// ---------------------------------------------------------------------------
__global__ __launch_bounds__(256) void prep_wt_kernel(
    const float* __restrict__ w_qs, const float* __restrict__ w_ks, const float* __restrict__ w_vs,
    const float* __restrict__ w_q,  const float* __restrict__ w_k,  const float* __restrict__ w_v,
    const float* __restrict__ w_qe, const float* __restrict__ w_ke, const float* __restrict__ w_ve,
    __hip_bfloat16* __restrict__ wth, __hip_bfloat16* __restrict__ wtl)
{
    const int i = blockIdx.x * 256 + threadIdx.x;     // 9*64*512
    const int matIdx = i >> 15;
    const int rem = i & 32767;
    const int col = rem >> 9, k = rem & 511;
    const float* W =
        (matIdx == 0) ? w_qs : (matIdx == 1) ? w_ks : (matIdx == 2) ? w_vs :
        (matIdx == 3) ? w_q  : (matIdx == 4) ? w_k  : (matIdx == 5) ? w_v  :
        (matIdx == 6) ? w_qe : (matIdx == 7) ? w_ke : w_ve;
    float f = W[(size_t)k * DK + col];
    __hip_bfloat16 h = __float2bfloat16(f);
    wth[i] = h;
    wtl[i] = __float2bfloat16(f - __bfloat162float(h));
}

// cope (DK x T f32) -> copeT (T x DK bf16)
__global__ __launch_bounds__(256) void prep_cope_kernel(
    const float* __restrict__ cope, __hip_bfloat16* __restrict__ copeT)
{
    const int i = blockIdx.x * 256 + threadIdx.x;
    const int m = i >> 6, d = i & 63;
    copeT[i] = __float2bfloat16(cope[(size_t)d * T + m]);
}

// ---------------------------------------------------------------------------
// QKV GEMM: 64-row tile x one matrix (Q/K/V) per block; K=512.
// ---------------------------------------------------------------------------
__global__ __launch_bounds__(256) void qkv_gemm_kernel(
    const __hip_bfloat16* __restrict__ xnh, const __hip_bfloat16* __restrict__ xnl,
    const __hip_bfloat16* __restrict__ wth, const __hip_bfloat16* __restrict__ wtl,
    __hip_bfloat16* __restrict__ qh, __hip_bfloat16* __restrict__ ql,
    __hip_bfloat16* __restrict__ kh, __hip_bfloat16* __restrict__ kl,
    __hip_bfloat16* __restrict__ vT)
{
    const int bid = blockIdx.x;
    const int mt = bid / 3, mat = bid % 3;
    const int r0 = mt * 64;
    const int b  = r0 / T, t0 = r0 % T;
    const int region = (t0 < S_LEN) ? 0 : (t0 < T - S_LEN) ? 1 : 2;
    const int matIdx = region * 3 + mat;

    const int tid = threadIdx.x, lane = tid & 63, wid = tid >> 6;
    const int wm = wid >> 1, wn = wid & 1;
    const int fr = lane & 15, k8 = (lane >> 4) * 8;

    f32x4 acc[2][2];
#pragma unroll
    for (int mf = 0; mf < 2; ++mf)
#pragma unroll
        for (int nf = 0; nf < 2; ++nf) acc[mf][nf] = (f32x4){0.f, 0.f, 0.f, 0.f};

    for (int ks = 0; ks < D_IN / 32; ++ks) {
        const int k = ks * 32 + k8;
        short8 ah[2], al[2], bh2[2], bl2[2];
#pragma unroll
        for (int mf = 0; mf < 2; ++mf) {
            size_t off = (size_t)(r0 + wm * 32 + mf * 16 + fr) * D_IN + k;
            ah[mf] = *(const short8*)(xnh + off);
            al[mf] = *(const short8*)(xnl + off);
        }
#pragma unroll
        for (int nf = 0; nf < 2; ++nf) {
            size_t off = ((size_t)matIdx * DK + wn * 32 + nf * 16 + fr) * D_IN + k;
            bh2[nf] = *(const short8*)(wth + off);
            bl2[nf] = *(const short8*)(wtl + off);
        }
#pragma unroll
        for (int mf = 0; mf < 2; ++mf)
#pragma unroll
            for (int nf = 0; nf < 2; ++nf) {
                acc[mf][nf] = __builtin_amdgcn_mfma_f32_16x16x32_bf16(ah[mf], bh2[nf], acc[mf][nf], 0, 0, 0);
                acc[mf][nf] = __builtin_amdgcn_mfma_f32_16x16x32_bf16(ah[mf], bl2[nf], acc[mf][nf], 0, 0, 0);
                acc[mf][nf] = __builtin_amdgcn_mfma_f32_16x16x32_bf16(al[mf], bh2[nf], acc[mf][nf], 0, 0, 0);
            }
    }

    const int r4 = (lane >> 4) * 4;
#pragma unroll
    for (int mf = 0; mf < 2; ++mf)
#pragma unroll
        for (int nf = 0; nf < 2; ++nf) {
            const int cg = wn * 32 + nf * 16 + fr;
#pragma unroll
            for (int j = 0; j < 4; ++j) {
                const int rg = r0 + wm * 32 + mf * 16 + r4 + j;
                float f = acc[mf][nf][j];
                __hip_bfloat16 h  = __float2bfloat16(f);
                __hip_bfloat16 lo = __float2bfloat16(f - __bfloat162float(h));
                if (mat == 0)      { qh[(size_t)rg * DK + cg] = h; ql[(size_t)rg * DK + cg] = lo; }
                else if (mat == 1) { kh[(size_t)rg * DK + cg] = h; kl[(size_t)rg * DK + cg] = lo; }
                else               { vT[((size_t)b * DK + cg) * T + (rg % T)] = h; }
            }
        }
}

// ---------------------------------------------------------------------------
// GEMM1: logits_c = q.k (split-bf16, 3 passes ~ f32); li_c = q.cope (bf16).
// ---------------------------------------------------------------------------
__global__ __launch_bounds__(256) void gemm1_kernel(
    const __hip_bfloat16* __restrict__ qh, const __hip_bfloat16* __restrict__ ql,
    const __hip_bfloat16* __restrict__ kh, const __hip_bfloat16* __restrict__ kl,
    const __hip_bfloat16* __restrict__ copeT,
    float* __restrict__ logits_c, __hip_bfloat16* __restrict__ li_c,
    int b, int t_off)
{
    constexpr int TS = T / 64;  // 40
    const int ti  = blockIdx.x / TS, si = blockIdx.x % TS;
    const int t0  = ti * 128, s0 = si * 64;
    const int tid = threadIdx.x, lane = tid & 63, wid = tid >> 6;
    const int wm  = wid >> 1, wn = wid & 1;
    const int fr  = lane & 15, k8 = (lane >> 4) * 8;
    const size_t qb = (size_t)b * T * DK;

    short8 ah[4][2], al[4][2];
#pragma unroll
    for (int mf = 0; mf < 4; ++mf)
#pragma unroll
        for (int ks = 0; ks < 2; ++ks) {
            size_t off = qb + (size_t)(t_off + t0 + wm * 64 + mf * 16 + fr) * DK + ks * 32 + k8;
            ah[mf][ks] = *(const short8*)(qh + off);
            al[mf][ks] = *(const short8*)(ql + off);
        }
    short8 bh[2][2], bl[2][2], bc[2][2];
#pragma unroll
    for (int nf = 0; nf < 2; ++nf)
#pragma unroll
        for (int ks = 0; ks < 2; ++ks) {
            size_t off = (size_t)(s0 + wn * 32 + nf * 16 + fr) * DK + ks * 32 + k8;
            bh[nf][ks] = *(const short8*)(kh + qb + off);
            bl[nf][ks] = *(const short8*)(kl + qb + off);
            bc[nf][ks] = *(const short8*)(copeT + off);
        }

    f32x4 accL[4][2], accM[4][2];
#pragma unroll
    for (int mf = 0; mf < 4; ++mf)
#pragma unroll
        for (int nf = 0; nf < 2; ++nf) {
            accL[mf][nf] = (f32x4){0.f, 0.f, 0.f, 0.f};
            accM[mf][nf] = (f32x4){0.f, 0.f, 0.f, 0.f};
        }

#pragma unroll
    for (int mf = 0; mf < 4; ++mf)
#pragma unroll
        for (int nf = 0; nf < 2; ++nf)
#pragma unroll
            for (int ks = 0; ks < 2; ++ks) {
                accL[mf][nf] = __builtin_amdgcn_mfma_f32_16x16x32_bf16(ah[mf][ks], bh[nf][ks], accL[mf][nf], 0, 0, 0);
                accL[mf][nf] = __builtin_amdgcn_mfma_f32_16x16x32_bf16(ah[mf][ks], bl[nf][ks], accL[mf][nf], 0, 0, 0);
                accL[mf][nf] = __builtin_amdgcn_mfma_f32_16x16x32_bf16(al[mf][ks], bh[nf][ks], accL[mf][nf], 0, 0, 0);
                accM[mf][nf] = __builtin_amdgcn_mfma_f32_16x16x32_bf16(ah[mf][ks], bc[nf][ks], accM[mf][nf], 0, 0, 0);
            }

    const int r4 = (lane >> 4) * 4;
#pragma unroll
    for (int mf = 0; mf < 4; ++mf)
#pragma unroll
        for (int nf = 0; nf < 2; ++nf) {
            const int cg = s0 + wn * 32 + nf * 16 + fr;
#pragma unroll
            for (int j = 0; j < 4; ++j) {
                const int rl = t0 + wm * 64 + mf * 16 + r4 + j;
                const size_t o = (size_t)rl * T + cg;
                logits_c[o] = accL[mf][nf][j];
                li_c[o]     = __float2bfloat16(accM[mf][nf][j]);
            }
        }
}

// ---------------------------------------------------------------------------
// Phase 2 v2: logits row -> registers (10/thread); li -> LDS (gather table);
// barrier-free wave scan + cross-wave fixup; emits p split-bf16 (ph/pl).
// ---------------------------------------------------------------------------
__global__ __launch_bounds__(256) void phase2_kernel(
    const float* __restrict__ logits_c, const __hip_bfloat16* __restrict__ li_c,
    __hip_bfloat16* __restrict__ ph, __hip_bfloat16* __restrict__ pl,
    int t_off)
{
    constexpr int CH = T / 256;  // 10
    const int tid  = threadIdx.x;
    const int lane = tid & 63;
    const int wv   = tid >> 6;
    const int rl   = blockIdx.x;
    const int t    = t_off + rl;

    __shared__ __hip_bfloat16 sli[T];          // 5 KB gather table
    __shared__ float redS[4], redM[4], redE[4];

    const float*          lrow  = logits_c + (size_t)rl * T;
    const __hip_bfloat16* lirow = li_c     + (size_t)rl * T;

    // li -> LDS, dword-coalesced
#pragma unroll
    for (int i = 0; i < 5; ++i) {
        const int idx = i * 256 + tid;         // uint index, T/2 = 1280 total
        ((unsigned int*)sli)[idx] = ((const unsigned int*)lirow)[idx];
    }

    // logits -> registers, sigmoid, thread-local sum
    const int s0 = tid * CH;
    float lg[CH], g[CH];
    float lsum = 0.f;
#pragma unroll
    for (int i = 0; i < CH; ++i) lg[i] = lrow[s0 + i];
#pragma unroll
    for (int i = 0; i < CH; ++i) {
        g[i] = 1.0f / (1.0f + __expf(-lg[i]));
        lsum += g[i];
    }

    // wave-inclusive scan of lsum (no barriers)
    float incl = lsum;
#pragma unroll
    for (int off = 1; off < 64; off <<= 1) {
        float n = __shfl_up(incl, off);
        if (lane >= off) incl += n;
    }
    if (lane == 63) redS[wv] = incl;
    __syncthreads();                            // covers sli + redS
    float total = 0.f, wpre = 0.f;
#pragma unroll
    for (int w2 = 0; w2 < 4; ++w2) {
        float tw = redS[w2];
        total += tw;
        if (w2 < wv) wpre += tw;
    }
    float run = wpre + incl - lsum;             // exclusive prefix of gates

    // CoPE bias + causal mask
    float att[CH];
    float lmax = -INFINITY;
#pragma unroll
    for (int i = 0; i < CH; ++i) {
        int s = s0 + i;
        float pos = total - run;                // sum_{s' >= s} gates
        run += g[i];
        pos = fminf(pos, (float)(T - 1));
        float pf = floorf(pos);
        float w  = pos - pf;
        int ipf  = (int)pf;
        int ipc  = (int)ceilf(pos);
        float bias = __bfloat162float(sli[ipc]) * w
                   + __bfloat162float(sli[ipf]) * (1.0f - w);
        float al = lg[i] * 0.125f + bias;
        if (s > t) al = -INFINITY;
        att[i] = al;
        lmax = fmaxf(lmax, al);
    }

#pragma unroll
    for (int off = 32; off > 0; off >>= 1) lmax = fmaxf(lmax, __shfl_down(lmax, off));
    if (lane == 0) redM[wv] = lmax;
    __syncthreads();
    const float bmax = fmaxf(fmaxf(redM[0], redM[1]), fmaxf(redM[2], redM[3]));

    float e[CH];
    float esum = 0.f;
#pragma unroll
    for (int i = 0; i < CH; ++i) {
        e[i] = __expf(att[i] - bmax);           // exp(-inf)=0 covers mask
        esum += e[i];
    }
#pragma unroll
    for (int off = 32; off > 0; off >>= 1) esum += __shfl_down(esum, off);
    if (lane == 0) redE[wv] = esum;
    __syncthreads();
    const float rden = 1.0f / (redE[0] + redE[1] + redE[2] + redE[3]);

    // p -> split bf16, packed dword stores (5 per thread per buffer)
    unsigned int hw[5], lw[5];
#pragma unroll
    for (int i = 0; i < 5; ++i) {
        float p0 = e[2 * i] * rden, p1 = e[2 * i + 1] * rden;
        __hip_bfloat16 h0 = __float2bfloat16(p0);
        __hip_bfloat16 h1 = __float2bfloat16(p1);
        __hip_bfloat16 l0 = __float2bfloat16(p0 - __bfloat162float(h0));
        __hip_bfloat16 l1 = __float2bfloat16(p1 - __bfloat162float(h1));
        hw[i] = (unsigned int)*(unsigned short*)&h0 | ((unsigned int)*(unsigned short*)&h1 << 16);
        lw[i] = (unsigned int)*(unsigned short*)&l0 | ((unsigned int)*(unsigned short*)&l1 << 16);
    }
    unsigned int* phw = (unsigned int*)(ph + (size_t)rl * T + s0);
    unsigned int* plw = (unsigned int*)(pl + (size_t)rl * T + s0);
#pragma unroll
    for (int i = 0; i < 5; ++i) { phw[i] = hw[i]; plw[i] = lw[i]; }
}

// ---------------------------------------------------------------------------
// GEMM2: out_part = P @ V, split-K SS chunks of 160; causal tile skip.
// ---------------------------------------------------------------------------
__global__ __launch_bounds__(256) void gemm2_kernel(
    const __hip_bfloat16* __restrict__ ph, const __hip_bfloat16* __restrict__ pl,
    const __hip_bfloat16* __restrict__ vT, float* __restrict__ part,
    int b, int t_off, int TC)
{
    const int ti  = blockIdx.x / SS, sc = blockIdx.x % SS;
    const int t0  = ti * 128;
    const int sb  = sc * (T / SS);
    if (sb > t_off + t0 + 127) return;          // fully above causal diagonal
    const int tid = threadIdx.x, lane = tid & 63, wid = tid >> 6;
    const int wm  = wid >> 1, wn = wid & 1;
    const int fr  = lane & 15, k8 = (lane >> 4) * 8;
    const size_t vb = (size_t)b * DK * T;

    f32x4 acc[4][2];
#pragma unroll
    for (int mf = 0; mf < 4; ++mf)
#pragma unroll
        for (int nf = 0; nf < 2; ++nf) acc[mf][nf] = (f32x4){0.f, 0.f, 0.f, 0.f};

    for (int ks = 0; ks < (T / SS) / 32; ++ks) {
        const int s = sb + ks * 32 + k8;
        short8 a_h[4], a_l[4], bv[2];
#pragma unroll
        for (int mf = 0; mf < 4; ++mf) {
            size_t off = (size_t)(t0 + wm * 64 + mf * 16 + fr) * T + s;
            a_h[mf] = *(const short8*)(ph + off);
            a_l[mf] = *(const short8*)(pl + off);
        }
#pragma unroll
        for (int nf = 0; nf < 2; ++nf)
            bv[nf] = *(const short8*)(vT + vb + (size_t)(wn * 32 + nf * 16 + fr) * T + s);
#pragma unroll
        for (int mf = 0; mf < 4; ++mf)
#pragma unroll
            for (int nf = 0; nf < 2; ++nf) {
                acc[mf][nf] = __builtin_amdgcn_mfma_f32_16x16x32_bf16(a_h[mf], bv[nf], acc[mf][nf], 0, 0, 0);
                acc[mf][nf] = __builtin_amdgcn_mfma_f32_16x16x32_bf16(a_l[mf], bv[nf], acc[mf][nf], 0, 0, 0);
            }
    }

    const int r4 = (lane >> 4) * 4;
#pragma unroll
    for (int mf = 0; mf < 4; ++mf)
#pragma unroll
        for (int nf = 0; nf < 2; ++nf) {
            const int cg = wn * 32 + nf * 16 + fr;
#pragma unroll
            for (int j = 0; j < 4; ++j) {
                const int rl = t0 + wm * 64 + mf * 16 + r4 + j;
                part[((size_t)sc * TC + rl) * DK + cg] = acc[mf][nf][j];
            }
        }
}

__global__ __launch_bounds__(256) void reduce_kernel(
    const float* __restrict__ part, float* __restrict__ out,
    int b, int t_off, int TC)
{
    const size_t i = (size_t)blockIdx.x * 256 + threadIdx.x;  // TC*DK total
    const int rl = (int)(i >> 6);
    const int t  = t_off + rl;
    const int sc_max = min(SS - 1, t / (T / SS));
    float s = 0.f;
    for (int sc = 0; sc <= sc_max; ++sc) s += part[(size_t)sc * TC * DK + i];
    out[((size_t)b * T + t_off) * DK + i] = s;
}

extern "C" void kernel_launch(void* const* d_in, const int* in_sizes, int n_in,
                              void* d_out, int out_size, void* d_ws, size_t ws_size,
                              hipStream_t stream)
{
    const float* x    = (const float*)d_in[0];
    const float* w_q  = (const float*)d_in[1];
    const float* w_k  = (const float*)d_in[2];
    const float* w_v  = (const float*)d_in[3];
    const float* w_qs = (const float*)d_in[4];
    const float* w_ks = (const float*)d_in[5];
    const float* w_vs = (const float*)d_in[6];
    const float* w_qe = (const float*)d_in[7];
    const float* w_ke = (const float*)d_in[8];
    const float* w_ve = (const float*)d_in[9];
    const float* g_m  = (const float*)d_in[10];
    const float* b_m  = (const float*)d_in[11];
    const float* g_s  = (const float*)d_in[12];
    const float* b_s  = (const float*)d_in[13];
    const float* g_e  = (const float*)d_in[14];
    const float* b_e  = (const float*)d_in[15];
    const float* cope = (const float*)d_in[16];

    const size_t n_qk  = (size_t)B_N * T * DK;
    const size_t n_xn  = (size_t)B_N * T * D_IN;
    const size_t n_wt  = (size_t)9 * DK * D_IN;
    const size_t fixed = 5 * n_qk * 2 + (size_t)T * DK * 2
                       + 2 * n_xn * 2 + 2 * n_wt * 2;
    auto chunk_bytes = [&](int TC) -> size_t {
        return fixed + (size_t)TC * T * 4 + 3 * (size_t)TC * T * 2
                     + (size_t)SS * TC * DK * 4;
    };
    int TC = 128;
    if (chunk_bytes(2560) <= ws_size)      TC = 2560;
    else if (chunk_bytes(1280) <= ws_size) TC = 1280;
    else if (chunk_bytes(640) <= ws_size)  TC = 640;

    char* w = (char*)d_ws;
    __hip_bfloat16* qh    = (__hip_bfloat16*)w; w += n_qk * 2;
    __hip_bfloat16* ql    = (__hip_bfloat16*)w; w += n_qk * 2;
    __hip_bfloat16* kh    = (__hip_bfloat16*)w; w += n_qk * 2;
    __hip_bfloat16* kl    = (__hip_bfloat16*)w; w += n_qk * 2;
    __hip_bfloat16* vT    = (__hip_bfloat16*)w; w += n_qk * 2;
    __hip_bfloat16* copeT = (__hip_bfloat16*)w; w += (size_t)T * DK * 2;
    __hip_bfloat16* xnh   = (__hip_bfloat16*)w; w += n_xn * 2;
    __hip_bfloat16* xnl   = (__hip_bfloat16*)w; w += n_xn * 2;
    __hip_bfloat16* wth   = (__hip_bfloat16*)w; w += n_wt * 2;
    __hip_bfloat16* wtl   = (__hip_bfloat16*)w; w += n_wt * 2;
    float*          logc  = (float*)w;          w += (size_t)TC * T * 4;
    __hip_bfloat16* lic   = (__hip_bfloat16*)w; w += (size_t)TC * T * 2;
    __hip_bfloat16* phbuf = (__hip_bfloat16*)w; w += (size_t)TC * T * 2;
    __hip_bfloat16* plbuf = (__hip_bfloat16*)w; w += (size_t)TC * T * 2;
    float*          part  = (float*)w;

    ln_kernel<<<B_N * T, 256, 0, stream>>>(
        x, g_m, b_m, g_s, b_s, g_e, b_e, xnh, xnl);

    prep_wt_kernel<<<(int)(n_wt / 256), 256, 0, stream>>>(
        w_qs, w_ks, w_vs, w_q, w_k, w_v, w_qe, w_ke, w_ve, wth, wtl);

    prep_cope_kernel<<<(T * DK) / 256, 256, 0, stream>>>(cope, copeT);

    qkv_gemm_kernel<<<(B_N * T / 64) * 3, 256, 0, stream>>>(
        xnh, xnl, wth, wtl, qh, ql, kh, kl, vT);

    for (int b = 0; b < B_N; ++b)
        for (int t_off = 0; t_off < T; t_off += TC) {
            gemm1_kernel<<<(TC / 128) * (T / 64), 256, 0, stream>>>(
                qh, ql, kh, kl, copeT, logc, lic, b, t_off);
            phase2_kernel<<<TC, 256, 0, stream>>>(
                logc, lic, phbuf, plbuf, t_off);
            gemm2_kernel<<<(TC / 128) * SS, 256, 0, stream>>>(
                phbuf, plbuf, vT, part, b, t_off, TC);
            reduce_kernel<<<(TC * DK) / 256, 256, 0, stream>>>(
                part, (float*)d_out, b, t_off, TC);
        }
}

// Round 7
// 116.340 us; speedup vs baseline: 1.2579x; 1.2579x over previous
//
#include <hip/hip_runtime.h>
#include <hip/hip_bf16.h>
#include <math.h>

using short8 = __attribute__((ext_vector_type(8))) short;
using f32x4  = __attribute__((ext_vector_type(4))) float;

constexpr int S_LEN  = 256;
constexpr int T      = 2560;
constexpr int D_IN   = 512;
constexpr int DK     = 64;
constexpr int B_N    = 2;
constexpr int SS     = 16;     // split-K chunks for PV (T/SS = 160 per chunk)

// ---------------------------------------------------------------------------
// LN: one row per WAVE (4 rows/block, no barriers); split bf16 out.
// ---------------------------------------------------------------------------
__global__ __launch_bounds__(256) void ln_kernel(
    const float* __restrict__ x,
    const float* __restrict__ g_m,  const float* __restrict__ b_m,
    const float* __restrict__ g_s,  const float* __restrict__ b_s,
    const float* __restrict__ g_e,  const float* __restrict__ b_e,
    __hip_bfloat16* __restrict__ xnh, __hip_bfloat16* __restrict__ xnl)
{
    const int wv   = threadIdx.x >> 6;
    const int lane = threadIdx.x & 63;
    const int row  = blockIdx.x * 4 + wv;
    const int t    = row % T;

    const float *gv, *bv;
    if (t < S_LEN)          { gv = g_s; bv = b_s; }
    else if (t < T - S_LEN) { gv = g_m; bv = b_m; }
    else                    { gv = g_e; bv = b_e; }

    const float4* xr4 = (const float4*)(x + (size_t)row * D_IN);
    float4 a = xr4[lane * 2], b4 = xr4[lane * 2 + 1];
    float xv[8] = {a.x, a.y, a.z, a.w, b4.x, b4.y, b4.z, b4.w};

    float s = 0.f;
#pragma unroll
    for (int j = 0; j < 8; ++j) s += xv[j];
#pragma unroll
    for (int off = 32; off > 0; off >>= 1) s += __shfl_down(s, off);
    s = __shfl(s, 0);
    const float mean = s * (1.0f / D_IN);

    float sq = 0.f;
#pragma unroll
    for (int j = 0; j < 8; ++j) { float d = xv[j] - mean; sq += d * d; }
#pragma unroll
    for (int off = 32; off > 0; off >>= 1) sq += __shfl_down(sq, off);
    sq = __shfl(sq, 0);
    const float inv = rsqrtf(sq * (1.0f / D_IN) + 1e-5f);

    const float4* gv4 = (const float4*)gv;
    const float4* bv4 = (const float4*)bv;
    float4 ga = gv4[lane * 2], gb = gv4[lane * 2 + 1];
    float4 ba = bv4[lane * 2], bb = bv4[lane * 2 + 1];
    float g8[8] = {ga.x, ga.y, ga.z, ga.w, gb.x, gb.y, gb.z, gb.w};
    float b8[8] = {ba.x, ba.y, ba.z, ba.w, bb.x, bb.y, bb.z, bb.w};

    short hs[8], ls[8];
#pragma unroll
    for (int j = 0; j < 8; ++j) {
        float v = (xv[j] - mean) * inv * g8[j] + b8[j];
        __hip_bfloat16 h  = __float2bfloat16(v);
        __hip_bfloat16 lo = __float2bfloat16(v - __bfloat162float(h));
        hs[j] = *(short*)&h;
        ls[j] = *(short*)&lo;
    }
    short8 H = {hs[0],hs[1],hs[2],hs[3],hs[4],hs[5],hs[6],hs[7]};
    short8 L = {ls[0],ls[1],ls[2],ls[3],ls[4],ls[5],ls[6],ls[7]};
    *(short8*)(xnh + (size_t)row * D_IN + lane * 8) = H;
    *(short8*)(xnl + (size_t)row * D_IN + lane * 8) = L;
}

// ---------------------------------------------------------------------------
// prep: 9 weight mats -> WT[9][64][512] split bf16, AND copeT (T x DK bf16)
// ---------------------------------------------------------------------------
__global__ __launch_bounds__(256) void prep_kernel(
    const float* __restrict__ w_qs, const float* __restrict__ w_ks, const float* __restrict__ w_vs,
    const float* __restrict__ w_q,  const float* __restrict__ w_k,  const float* __restrict__ w_v,
    const float* __restrict__ w_qe, const float* __restrict__ w_ke, const float* __restrict__ w_ve,
    const float* __restrict__ cope,
    __hip_bfloat16* __restrict__ wth, __hip_bfloat16* __restrict__ wtl,
    __hip_bfloat16* __restrict__ copeT)
{
    const int i = blockIdx.x * 256 + threadIdx.x;
    constexpr int NW = 9 * DK * D_IN;          // 294912
    if (i < NW) {
        const int matIdx = i >> 15;
        const int rem = i & 32767;
        const int col = rem >> 9, k = rem & 511;
        const float* W =
            (matIdx == 0) ? w_qs : (matIdx == 1) ? w_ks : (matIdx == 2) ? w_vs :
            (matIdx == 3) ? w_q  : (matIdx == 4) ? w_k  : (matIdx == 5) ? w_v  :
            (matIdx == 6) ? w_qe : (matIdx == 7) ? w_ke : w_ve;
        float f = W[(size_t)k * DK + col];
        __hip_bfloat16 h = __float2bfloat16(f);
        wth[i] = h;
        wtl[i] = __float2bfloat16(f - __bfloat162float(h));
    } else {
        const int j = i - NW;                  // < T*DK = 163840
        const int m = j >> 6, d = j & 63;
        copeT[j] = __float2bfloat16(cope[(size_t)d * T + m]);
    }
}

// ---------------------------------------------------------------------------
// QKV GEMM: 64-row tile x one matrix (Q/K/V) per block; K=512.
// ---------------------------------------------------------------------------
__global__ __launch_bounds__(256) void qkv_gemm_kernel(
    const __hip_bfloat16* __restrict__ xnh, const __hip_bfloat16* __restrict__ xnl,
    const __hip_bfloat16* __restrict__ wth, const __hip_bfloat16* __restrict__ wtl,
    __hip_bfloat16* __restrict__ qh, __hip_bfloat16* __restrict__ ql,
    __hip_bfloat16* __restrict__ kh, __hip_bfloat16* __restrict__ kl,
    __hip_bfloat16* __restrict__ vT)
{
    const int bid = blockIdx.x;
    const int mt = bid / 3, mat = bid % 3;
    const int r0 = mt * 64;
    const int b  = r0 / T, t0 = r0 % T;
    const int region = (t0 < S_LEN) ? 0 : (t0 < T - S_LEN) ? 1 : 2;
    const int matIdx = region * 3 + mat;

    const int tid = threadIdx.x, lane = tid & 63, wid = tid >> 6;
    const int wm = wid >> 1, wn = wid & 1;
    const int fr = lane & 15, k8 = (lane >> 4) * 8;

    f32x4 acc[2][2];
#pragma unroll
    for (int mf = 0; mf < 2; ++mf)
#pragma unroll
        for (int nf = 0; nf < 2; ++nf) acc[mf][nf] = (f32x4){0.f, 0.f, 0.f, 0.f};

    for (int ks = 0; ks < D_IN / 32; ++ks) {
        const int k = ks * 32 + k8;
        short8 ah[2], al[2], bh2[2], bl2[2];
#pragma unroll
        for (int mf = 0; mf < 2; ++mf) {
            size_t off = (size_t)(r0 + wm * 32 + mf * 16 + fr) * D_IN + k;
            ah[mf] = *(const short8*)(xnh + off);
            al[mf] = *(const short8*)(xnl + off);
        }
#pragma unroll
        for (int nf = 0; nf < 2; ++nf) {
            size_t off = ((size_t)matIdx * DK + wn * 32 + nf * 16 + fr) * D_IN + k;
            bh2[nf] = *(const short8*)(wth + off);
            bl2[nf] = *(const short8*)(wtl + off);
        }
#pragma unroll
        for (int mf = 0; mf < 2; ++mf)
#pragma unroll
            for (int nf = 0; nf < 2; ++nf) {
                acc[mf][nf] = __builtin_amdgcn_mfma_f32_16x16x32_bf16(ah[mf], bh2[nf], acc[mf][nf], 0, 0, 0);
                acc[mf][nf] = __builtin_amdgcn_mfma_f32_16x16x32_bf16(ah[mf], bl2[nf], acc[mf][nf], 0, 0, 0);
                acc[mf][nf] = __builtin_amdgcn_mfma_f32_16x16x32_bf16(al[mf], bh2[nf], acc[mf][nf], 0, 0, 0);
            }
    }

    const int r4 = (lane >> 4) * 4;
#pragma unroll
    for (int mf = 0; mf < 2; ++mf)
#pragma unroll
        for (int nf = 0; nf < 2; ++nf) {
            const int cg = wn * 32 + nf * 16 + fr;
#pragma unroll
            for (int j = 0; j < 4; ++j) {
                const int rg = r0 + wm * 32 + mf * 16 + r4 + j;
                float f = acc[mf][nf][j];
                __hip_bfloat16 h  = __float2bfloat16(f);
                __hip_bfloat16 lo = __float2bfloat16(f - __bfloat162float(h));
                if (mat == 0)      { qh[(size_t)rg * DK + cg] = h; ql[(size_t)rg * DK + cg] = lo; }
                else if (mat == 1) { kh[(size_t)rg * DK + cg] = h; kl[(size_t)rg * DK + cg] = lo; }
                else               { vT[((size_t)b * DK + cg) * T + (rg % T)] = h; }
            }
        }
}

// ---------------------------------------------------------------------------
// GEMM1: logits = q.k (split-bf16, 3 passes ~ f32); li = q.cope (bf16).
// Grid covers NB batches x (TC/128) x (T/64).
// ---------------------------------------------------------------------------
__global__ __launch_bounds__(256) void gemm1_kernel(
    const __hip_bfloat16* __restrict__ qh, const __hip_bfloat16* __restrict__ ql,
    const __hip_bfloat16* __restrict__ kh, const __hip_bfloat16* __restrict__ kl,
    const __hip_bfloat16* __restrict__ copeT,
    float* __restrict__ logc, __hip_bfloat16* __restrict__ lic,
    int b0, int t_off, int TC)
{
    constexpr int TS = T / 64;  // 40
    const int per_b = (TC / 128) * TS;
    const int bb  = blockIdx.x / per_b;
    const int rem = blockIdx.x % per_b;
    const int ti  = rem / TS, si = rem % TS;
    const int t0  = ti * 128, s0 = si * 64;
    const int b   = b0 + bb;
    float*          logits_c = logc + (size_t)bb * TC * T;
    __hip_bfloat16* li_c     = lic  + (size_t)bb * TC * T;

    const int tid = threadIdx.x, lane = tid & 63, wid = tid >> 6;
    const int wm  = wid >> 1, wn = wid & 1;
    const int fr  = lane & 15, k8 = (lane >> 4) * 8;
    const size_t qb = (size_t)b * T * DK;

    short8 ah[4][2], al[4][2];
#pragma unroll
    for (int mf = 0; mf < 4; ++mf)
#pragma unroll
        for (int ks = 0; ks < 2; ++ks) {
            size_t off = qb + (size_t)(t_off + t0 + wm * 64 + mf * 16 + fr) * DK + ks * 32 + k8;
            ah[mf][ks] = *(const short8*)(qh + off);
            al[mf][ks] = *(const short8*)(ql + off);
        }
    short8 bh[2][2], bl[2][2], bc[2][2];
#pragma unroll
    for (int nf = 0; nf < 2; ++nf)
#pragma unroll
        for (int ks = 0; ks < 2; ++ks) {
            size_t off = (size_t)(s0 + wn * 32 + nf * 16 + fr) * DK + ks * 32 + k8;
            bh[nf][ks] = *(const short8*)(kh + qb + off);
            bl[nf][ks] = *(const short8*)(kl + qb + off);
            bc[nf][ks] = *(const short8*)(copeT + off);
        }

    f32x4 accL[4][2], accM[4][2];
#pragma unroll
    for (int mf = 0; mf < 4; ++mf)
#pragma unroll
        for (int nf = 0; nf < 2; ++nf) {
            accL[mf][nf] = (f32x4){0.f, 0.f, 0.f, 0.f};
            accM[mf][nf] = (f32x4){0.f, 0.f, 0.f, 0.f};
        }

#pragma unroll
    for (int mf = 0; mf < 4; ++mf)
#pragma unroll
        for (int nf = 0; nf < 2; ++nf)
#pragma unroll
            for (int ks = 0; ks < 2; ++ks) {
                accL[mf][nf] = __builtin_amdgcn_mfma_f32_16x16x32_bf16(ah[mf][ks], bh[nf][ks], accL[mf][nf], 0, 0, 0);
                accL[mf][nf] = __builtin_amdgcn_mfma_f32_16x16x32_bf16(ah[mf][ks], bl[nf][ks], accL[mf][nf], 0, 0, 0);
                accL[mf][nf] = __builtin_amdgcn_mfma_f32_16x16x32_bf16(al[mf][ks], bh[nf][ks], accL[mf][nf], 0, 0, 0);
                accM[mf][nf] = __builtin_amdgcn_mfma_f32_16x16x32_bf16(ah[mf][ks], bc[nf][ks], accM[mf][nf], 0, 0, 0);
            }

    const int r4 = (lane >> 4) * 4;
#pragma unroll
    for (int mf = 0; mf < 4; ++mf)
#pragma unroll
        for (int nf = 0; nf < 2; ++nf) {
            const int cg = s0 + wn * 32 + nf * 16 + fr;
#pragma unroll
            for (int j = 0; j < 4; ++j) {
                const int rl = t0 + wm * 64 + mf * 16 + r4 + j;
                const size_t o = (size_t)rl * T + cg;
                logits_c[o] = accL[mf][nf][j];
                li_c[o]     = __float2bfloat16(accM[mf][nf][j]);
            }
        }
}

// ---------------------------------------------------------------------------
// Phase 2: logits -> registers; li -> LDS; wave scan + fixup; p f32 in place.
// Grid covers NB x TC rows.
// ---------------------------------------------------------------------------
__global__ __launch_bounds__(256) void phase2_kernel(
    float* __restrict__ logc, const __hip_bfloat16* __restrict__ lic,
    int t_off, int TC)
{
    constexpr int CH = T / 256;  // 10
    const int tid  = threadIdx.x;
    const int lane = tid & 63;
    const int wv   = tid >> 6;
    const int bb   = blockIdx.x / TC;
    const int rl   = blockIdx.x % TC;
    const int t    = t_off + rl;

    __shared__ __hip_bfloat16 sli[T];          // 5 KB gather table
    __shared__ float redS[4], redM[4], redE[4];

    float*                lrow  = logc + ((size_t)bb * TC + rl) * T;
    const __hip_bfloat16* lirow = lic  + ((size_t)bb * TC + rl) * T;

    // li -> LDS, dword-coalesced
#pragma unroll
    for (int i = 0; i < 5; ++i) {
        const int idx = i * 256 + tid;
        ((unsigned int*)sli)[idx] = ((const unsigned int*)lirow)[idx];
    }

    // logits -> registers (float2), sigmoid, thread-local sum
    const int s0 = tid * CH;
    float lg[CH], g[CH];
    float lsum = 0.f;
    const float2* lr2 = (const float2*)(lrow + s0);
#pragma unroll
    for (int i = 0; i < 5; ++i) {
        float2 v = lr2[i];
        lg[2 * i] = v.x; lg[2 * i + 1] = v.y;
    }
#pragma unroll
    for (int i = 0; i < CH; ++i) {
        g[i] = 1.0f / (1.0f + __expf(-lg[i]));
        lsum += g[i];
    }

    // wave-inclusive scan of lsum
    float incl = lsum;
#pragma unroll
    for (int off = 1; off < 64; off <<= 1) {
        float n = __shfl_up(incl, off);
        if (lane >= off) incl += n;
    }
    if (lane == 63) redS[wv] = incl;
    __syncthreads();                            // covers sli + redS
    float total = 0.f, wpre = 0.f;
#pragma unroll
    for (int w2 = 0; w2 < 4; ++w2) {
        float tw = redS[w2];
        total += tw;
        if (w2 < wv) wpre += tw;
    }
    float run = wpre + incl - lsum;

    // CoPE bias + causal mask
    float att[CH];
    float lmax = -INFINITY;
#pragma unroll
    for (int i = 0; i < CH; ++i) {
        int s = s0 + i;
        float pos = total - run;
        run += g[i];
        pos = fminf(pos, (float)(T - 1));
        float pf = floorf(pos);
        float w  = pos - pf;
        int ipf  = (int)pf;
        int ipc  = (int)ceilf(pos);
        float bias = __bfloat162float(sli[ipc]) * w
                   + __bfloat162float(sli[ipf]) * (1.0f - w);
        float al = lg[i] * 0.125f + bias;
        if (s > t) al = -INFINITY;
        att[i] = al;
        lmax = fmaxf(lmax, al);
    }

#pragma unroll
    for (int off = 32; off > 0; off >>= 1) lmax = fmaxf(lmax, __shfl_down(lmax, off));
    if (lane == 0) redM[wv] = lmax;
    __syncthreads();
    const float bmax = fmaxf(fmaxf(redM[0], redM[1]), fmaxf(redM[2], redM[3]));

    float e[CH];
    float esum = 0.f;
#pragma unroll
    for (int i = 0; i < CH; ++i) {
        e[i] = __expf(att[i] - bmax);           // exp(-inf)=0 covers mask
        esum += e[i];
    }
#pragma unroll
    for (int off = 32; off > 0; off >>= 1) esum += __shfl_down(esum, off);
    if (lane == 0) redE[wv] = esum;
    __syncthreads();
    const float rden = 1.0f / (redE[0] + redE[1] + redE[2] + redE[3]);

    float2* pw = (float2*)(lrow + s0);
#pragma unroll
    for (int i = 0; i < 5; ++i)
        pw[i] = make_float2(e[2 * i] * rden, e[2 * i + 1] * rden);
}

// ---------------------------------------------------------------------------
// GEMM2: out_part = P @ V; P read f32, split-bf16 in-register; causal skip.
// Grid covers NB x (TC/128) x SS.
// ---------------------------------------------------------------------------
__global__ __launch_bounds__(256) void gemm2_kernel(
    const float* __restrict__ logc, const __hip_bfloat16* __restrict__ vT,
    float* __restrict__ part, int b0, int t_off, int TC)
{
    const int per_b = (TC / 128) * SS;
    const int bb  = blockIdx.x / per_b;
    const int rem = blockIdx.x % per_b;
    const int ti  = rem / SS, sc = rem % SS;
    const int t0  = ti * 128;
    const int sb  = sc * (T / SS);
    if (sb > t_off + t0 + 127) return;          // fully above causal diagonal
    const int b   = b0 + bb;
    const float* p_c = logc + (size_t)bb * TC * T;

    const int tid = threadIdx.x, lane = tid & 63, wid = tid >> 6;
    const int wm  = wid >> 1, wn = wid & 1;
    const int fr  = lane & 15, k8 = (lane >> 4) * 8;
    const size_t vb = (size_t)b * DK * T;

    f32x4 acc[4][2];
#pragma unroll
    for (int mf = 0; mf < 4; ++mf)
#pragma unroll
        for (int nf = 0; nf < 2; ++nf) acc[mf][nf] = (f32x4){0.f, 0.f, 0.f, 0.f};

    for (int ks = 0; ks < (T / SS) / 32; ++ks) {   // 5 k-steps
        const int s = sb + ks * 32 + k8;
        short8 a_h[4], a_l[4], bv[2];
#pragma unroll
        for (int mf = 0; mf < 4; ++mf) {
            const float* pp = p_c + (size_t)(t0 + wm * 64 + mf * 16 + fr) * T + s;
            short hh[8], ll[8];
#pragma unroll
            for (int j = 0; j < 8; ++j) {
                float p = pp[j];
                __hip_bfloat16 h  = __float2bfloat16(p);
                __hip_bfloat16 lo = __float2bfloat16(p - __bfloat162float(h));
                hh[j] = *(short*)&h;
                ll[j] = *(short*)&lo;
            }
            a_h[mf] = (short8){hh[0],hh[1],hh[2],hh[3],hh[4],hh[5],hh[6],hh[7]};
            a_l[mf] = (short8){ll[0],ll[1],ll[2],ll[3],ll[4],ll[5],ll[6],ll[7]};
        }
#pragma unroll
        for (int nf = 0; nf < 2; ++nf)
            bv[nf] = *(const short8*)(vT + vb + (size_t)(wn * 32 + nf * 16 + fr) * T + s);
#pragma unroll
        for (int mf = 0; mf < 4; ++mf)
#pragma unroll
            for (int nf = 0; nf < 2; ++nf) {
                acc[mf][nf] = __builtin_amdgcn_mfma_f32_16x16x32_bf16(a_h[mf], bv[nf], acc[mf][nf], 0, 0, 0);
                acc[mf][nf] = __builtin_amdgcn_mfma_f32_16x16x32_bf16(a_l[mf], bv[nf], acc[mf][nf], 0, 0, 0);
            }
    }

    const int r4 = (lane >> 4) * 4;
#pragma unroll
    for (int mf = 0; mf < 4; ++mf)
#pragma unroll
        for (int nf = 0; nf < 2; ++nf) {
            const int cg = wn * 32 + nf * 16 + fr;
#pragma unroll
            for (int j = 0; j < 4; ++j) {
                const int rl = t0 + wm * 64 + mf * 16 + r4 + j;
                part[(((size_t)bb * SS + sc) * TC + rl) * DK + cg] = acc[mf][nf][j];
            }
        }
}

__global__ __launch_bounds__(256) void reduce_kernel(
    const float* __restrict__ part, float* __restrict__ out,
    int b0, int t_off, int TC)
{
    const int per_b = (TC * DK) / 256;
    const int bb = blockIdx.x / per_b;
    const int ii = (blockIdx.x % per_b) * 256 + threadIdx.x;  // < TC*DK
    const int rl = ii >> 6, d = ii & 63;
    const int t  = t_off + rl;
    const int sc_max = min(SS - 1, t / (T / SS));
    float s = 0.f;
    for (int sc = 0; sc <= sc_max; ++sc)
        s += part[(((size_t)bb * SS + sc) * TC + rl) * DK + d];
    out[((size_t)(b0 + bb) * T + t) * DK + d] = s;
}

extern "C" void kernel_launch(void* const* d_in, const int* in_sizes, int n_in,
                              void* d_out, int out_size, void* d_ws, size_t ws_size,
                              hipStream_t stream)
{
    const float* x    = (const float*)d_in[0];
    const float* w_q  = (const float*)d_in[1];
    const float* w_k  = (const float*)d_in[2];
    const float* w_v  = (const float*)d_in[3];
    const float* w_qs = (const float*)d_in[4];
    const float* w_ks = (const float*)d_in[5];
    const float* w_vs = (const float*)d_in[6];
    const float* w_qe = (const float*)d_in[7];
    const float* w_ke = (const float*)d_in[8];
    const float* w_ve = (const float*)d_in[9];
    const float* g_m  = (const float*)d_in[10];
    const float* b_m  = (const float*)d_in[11];
    const float* g_s  = (const float*)d_in[12];
    const float* b_s  = (const float*)d_in[13];
    const float* g_e  = (const float*)d_in[14];
    const float* b_e  = (const float*)d_in[15];
    const float* cope = (const float*)d_in[16];

    const size_t n_qk  = (size_t)B_N * T * DK;
    const size_t n_xn  = (size_t)B_N * T * D_IN;
    const size_t n_wt  = (size_t)9 * DK * D_IN;
    const size_t fixedB = 5 * n_qk * 2 + (size_t)T * DK * 2
                        + 2 * n_xn * 2 + 2 * n_wt * 2;
    auto chunkB = [&](size_t TC) -> size_t {
        return TC * (size_t)T * 4          // logits/p (f32, in-place)
             + TC * (size_t)T * 2          // li (bf16)
             + (size_t)SS * TC * DK * 4;   // part
    };
    int TC, NB;
    if (fixedB + 2 * chunkB(T) <= ws_size)       { TC = T;    NB = 2; }
    else if (fixedB + chunkB(T) <= ws_size)      { TC = T;    NB = 1; }
    else if (fixedB + chunkB(1280) <= ws_size)   { TC = 1280; NB = 1; }
    else                                         { TC = 640;  NB = 1; }

    char* w = (char*)d_ws;
    __hip_bfloat16* qh    = (__hip_bfloat16*)w; w += n_qk * 2;
    __hip_bfloat16* ql    = (__hip_bfloat16*)w; w += n_qk * 2;
    __hip_bfloat16* kh    = (__hip_bfloat16*)w; w += n_qk * 2;
    __hip_bfloat16* kl    = (__hip_bfloat16*)w; w += n_qk * 2;
    __hip_bfloat16* vT    = (__hip_bfloat16*)w; w += n_qk * 2;
    __hip_bfloat16* copeT = (__hip_bfloat16*)w; w += (size_t)T * DK * 2;
    __hip_bfloat16* xnh   = (__hip_bfloat16*)w; w += n_xn * 2;
    __hip_bfloat16* xnl   = (__hip_bfloat16*)w; w += n_xn * 2;
    __hip_bfloat16* wth   = (__hip_bfloat16*)w; w += n_wt * 2;
    __hip_bfloat16* wtl   = (__hip_bfloat16*)w; w += n_wt * 2;
    float*          logc  = (float*)w;          w += (size_t)NB * TC * T * 4;
    __hip_bfloat16* lic   = (__hip_bfloat16*)w; w += (size_t)NB * TC * T * 2;
    float*          part  = (float*)w;

    ln_kernel<<<(B_N * T) / 4, 256, 0, stream>>>(
        x, g_m, b_m, g_s, b_s, g_e, b_e, xnh, xnl);

    prep_kernel<<<(int)((n_wt + (size_t)T * DK) / 256), 256, 0, stream>>>(
        w_qs, w_ks, w_vs, w_q, w_k, w_v, w_qe, w_ke, w_ve, cope,
        wth, wtl, copeT);

    qkv_gemm_kernel<<<(B_N * T / 64) * 3, 256, 0, stream>>>(
        xnh, xnl, wth, wtl, qh, ql, kh, kl, vT);

    for (int b0 = 0; b0 < B_N; b0 += NB)
        for (int t_off = 0; t_off < T; t_off += TC) {
            gemm1_kernel<<<NB * (TC / 128) * (T / 64), 256, 0, stream>>>(
                qh, ql, kh, kl, copeT, logc, lic, b0, t_off, TC);
            phase2_kernel<<<NB * TC, 256, 0, stream>>>(
                logc, lic, t_off, TC);
            gemm2_kernel<<<NB * (TC / 128) * SS, 256, 0, stream>>>(
                logc, vT, part, b0, t_off, TC);
            reduce_kernel<<<NB * (TC * DK) / 256, 256, 0, stream>>>(
                part, (float*)d_out, b0, t_off, TC);
        }
}

// Round 8
// 105.590 us; speedup vs baseline: 1.3859x; 1.1018x over previous
//
#include <hip/hip_runtime.h>
#include <hip/hip_bf16.h>
#include <math.h>

using short8 = __attribute__((ext_vector_type(8))) short;
using f32x4  = __attribute__((ext_vector_type(4))) float;

constexpr int S_LEN  = 256;
constexpr int T      = 2560;
constexpr int D_IN   = 512;
constexpr int DK     = 64;
constexpr int B_N    = 2;
constexpr int SS     = 8;      // split-K chunks for PV (T/SS = 320 per chunk)

// ---------------------------------------------------------------------------
// LN (one row/wave) + weight/cope prep, merged: branch on blockIdx.
// ---------------------------------------------------------------------------
__global__ __launch_bounds__(256) void lnprep_kernel(
    const float* __restrict__ x,
    const float* __restrict__ g_m,  const float* __restrict__ b_m,
    const float* __restrict__ g_s,  const float* __restrict__ b_s,
    const float* __restrict__ g_e,  const float* __restrict__ b_e,
    const float* __restrict__ w_qs, const float* __restrict__ w_ks, const float* __restrict__ w_vs,
    const float* __restrict__ w_q,  const float* __restrict__ w_k,  const float* __restrict__ w_v,
    const float* __restrict__ w_qe, const float* __restrict__ w_ke, const float* __restrict__ w_ve,
    const float* __restrict__ cope,
    __hip_bfloat16* __restrict__ xnh, __hip_bfloat16* __restrict__ xnl,
    __hip_bfloat16* __restrict__ wth, __hip_bfloat16* __restrict__ wtl,
    __hip_bfloat16* __restrict__ copeT)
{
    constexpr int LN_BLOCKS = (B_N * T) / 4;   // 1280
    if (blockIdx.x < LN_BLOCKS) {
        const int wv   = threadIdx.x >> 6;
        const int lane = threadIdx.x & 63;
        const int row  = blockIdx.x * 4 + wv;
        const int t    = row % T;

        const float *gv, *bv;
        if (t < S_LEN)          { gv = g_s; bv = b_s; }
        else if (t < T - S_LEN) { gv = g_m; bv = b_m; }
        else                    { gv = g_e; bv = b_e; }

        const float4* xr4 = (const float4*)(x + (size_t)row * D_IN);
        float4 a = xr4[lane * 2], b4 = xr4[lane * 2 + 1];
        float xv[8] = {a.x, a.y, a.z, a.w, b4.x, b4.y, b4.z, b4.w};

        float s = 0.f;
#pragma unroll
        for (int j = 0; j < 8; ++j) s += xv[j];
#pragma unroll
        for (int off = 32; off > 0; off >>= 1) s += __shfl_down(s, off);
        s = __shfl(s, 0);
        const float mean = s * (1.0f / D_IN);

        float sq = 0.f;
#pragma unroll
        for (int j = 0; j < 8; ++j) { float d = xv[j] - mean; sq += d * d; }
#pragma unroll
        for (int off = 32; off > 0; off >>= 1) sq += __shfl_down(sq, off);
        sq = __shfl(sq, 0);
        const float inv = rsqrtf(sq * (1.0f / D_IN) + 1e-5f);

        const float4* gv4 = (const float4*)gv;
        const float4* bv4 = (const float4*)bv;
        float4 ga = gv4[lane * 2], gb = gv4[lane * 2 + 1];
        float4 ba = bv4[lane * 2], bb = bv4[lane * 2 + 1];
        float g8[8] = {ga.x, ga.y, ga.z, ga.w, gb.x, gb.y, gb.z, gb.w};
        float b8[8] = {ba.x, ba.y, ba.z, ba.w, bb.x, bb.y, bb.z, bb.w};

        short hs[8], ls[8];
#pragma unroll
        for (int j = 0; j < 8; ++j) {
            float v = (xv[j] - mean) * inv * g8[j] + b8[j];
            __hip_bfloat16 h  = __float2bfloat16(v);
            __hip_bfloat16 lo = __float2bfloat16(v - __bfloat162float(h));
            hs[j] = *(short*)&h;
            ls[j] = *(short*)&lo;
        }
        short8 H = {hs[0],hs[1],hs[2],hs[3],hs[4],hs[5],hs[6],hs[7]};
        short8 L = {ls[0],ls[1],ls[2],ls[3],ls[4],ls[5],ls[6],ls[7]};
        *(short8*)(xnh + (size_t)row * D_IN + lane * 8) = H;
        *(short8*)(xnl + (size_t)row * D_IN + lane * 8) = L;
        return;
    }

    const int i = (blockIdx.x - LN_BLOCKS) * 256 + threadIdx.x;
    constexpr int NW = 9 * DK * D_IN;          // 294912
    if (i < NW) {
        const int matIdx = i >> 15;
        const int rem = i & 32767;
        const int col = rem >> 9, k = rem & 511;
        const float* W =
            (matIdx == 0) ? w_qs : (matIdx == 1) ? w_ks : (matIdx == 2) ? w_vs :
            (matIdx == 3) ? w_q  : (matIdx == 4) ? w_k  : (matIdx == 5) ? w_v  :
            (matIdx == 6) ? w_qe : (matIdx == 7) ? w_ke : w_ve;
        float f = W[(size_t)k * DK + col];
        __hip_bfloat16 h = __float2bfloat16(f);
        wth[i] = h;
        wtl[i] = __float2bfloat16(f - __bfloat162float(h));
    } else if (i < NW + T * DK) {
        const int j = i - NW;                  // < T*DK = 163840
        const int m = j >> 6, d = j & 63;
        copeT[j] = __float2bfloat16(cope[(size_t)d * T + m]);
    }
}

// ---------------------------------------------------------------------------
// QKV GEMM: 64-row tile x one matrix (Q/K/V) per block; K=512.
// ---------------------------------------------------------------------------
__global__ __launch_bounds__(256) void qkv_gemm_kernel(
    const __hip_bfloat16* __restrict__ xnh, const __hip_bfloat16* __restrict__ xnl,
    const __hip_bfloat16* __restrict__ wth, const __hip_bfloat16* __restrict__ wtl,
    __hip_bfloat16* __restrict__ qh, __hip_bfloat16* __restrict__ ql,
    __hip_bfloat16* __restrict__ kh, __hip_bfloat16* __restrict__ kl,
    __hip_bfloat16* __restrict__ vT)
{
    const int bid = blockIdx.x;
    const int mt = bid / 3, mat = bid % 3;
    const int r0 = mt * 64;
    const int b  = r0 / T, t0 = r0 % T;
    const int region = (t0 < S_LEN) ? 0 : (t0 < T - S_LEN) ? 1 : 2;
    const int matIdx = region * 3 + mat;

    const int tid = threadIdx.x, lane = tid & 63, wid = tid >> 6;
    const int wm = wid >> 1, wn = wid & 1;
    const int fr = lane & 15, k8 = (lane >> 4) * 8;

    f32x4 acc[2][2];
#pragma unroll
    for (int mf = 0; mf < 2; ++mf)
#pragma unroll
        for (int nf = 0; nf < 2; ++nf) acc[mf][nf] = (f32x4){0.f, 0.f, 0.f, 0.f};

    for (int ks = 0; ks < D_IN / 32; ++ks) {
        const int k = ks * 32 + k8;
        short8 ah[2], al[2], bh2[2], bl2[2];
#pragma unroll
        for (int mf = 0; mf < 2; ++mf) {
            size_t off = (size_t)(r0 + wm * 32 + mf * 16 + fr) * D_IN + k;
            ah[mf] = *(const short8*)(xnh + off);
            al[mf] = *(const short8*)(xnl + off);
        }
#pragma unroll
        for (int nf = 0; nf < 2; ++nf) {
            size_t off = ((size_t)matIdx * DK + wn * 32 + nf * 16 + fr) * D_IN + k;
            bh2[nf] = *(const short8*)(wth + off);
            bl2[nf] = *(const short8*)(wtl + off);
        }
#pragma unroll
        for (int mf = 0; mf < 2; ++mf)
#pragma unroll
            for (int nf = 0; nf < 2; ++nf) {
                acc[mf][nf] = __builtin_amdgcn_mfma_f32_16x16x32_bf16(ah[mf], bh2[nf], acc[mf][nf], 0, 0, 0);
                acc[mf][nf] = __builtin_amdgcn_mfma_f32_16x16x32_bf16(ah[mf], bl2[nf], acc[mf][nf], 0, 0, 0);
                acc[mf][nf] = __builtin_amdgcn_mfma_f32_16x16x32_bf16(al[mf], bh2[nf], acc[mf][nf], 0, 0, 0);
            }
    }

    const int r4 = (lane >> 4) * 4;
#pragma unroll
    for (int mf = 0; mf < 2; ++mf)
#pragma unroll
        for (int nf = 0; nf < 2; ++nf) {
            const int cg = wn * 32 + nf * 16 + fr;
#pragma unroll
            for (int j = 0; j < 4; ++j) {
                const int rg = r0 + wm * 32 + mf * 16 + r4 + j;
                float f = acc[mf][nf][j];
                __hip_bfloat16 h  = __float2bfloat16(f);
                __hip_bfloat16 lo = __float2bfloat16(f - __bfloat162float(h));
                if (mat == 0)      { qh[(size_t)rg * DK + cg] = h; ql[(size_t)rg * DK + cg] = lo; }
                else if (mat == 1) { kh[(size_t)rg * DK + cg] = h; kl[(size_t)rg * DK + cg] = lo; }
                else               { vT[((size_t)b * DK + cg) * T + (rg % T)] = h; }
            }
        }
}

// ---------------------------------------------------------------------------
// GEMM1: logits = q.k (split-bf16, 3 passes ~ f32); li = q.cope (bf16).
// ---------------------------------------------------------------------------
__global__ __launch_bounds__(256) void gemm1_kernel(
    const __hip_bfloat16* __restrict__ qh, const __hip_bfloat16* __restrict__ ql,
    const __hip_bfloat16* __restrict__ kh, const __hip_bfloat16* __restrict__ kl,
    const __hip_bfloat16* __restrict__ copeT,
    float* __restrict__ logc, __hip_bfloat16* __restrict__ lic,
    int b0, int t_off, int TC)
{
    constexpr int TS = T / 64;  // 40
    const int per_b = (TC / 128) * TS;
    const int bb  = blockIdx.x / per_b;
    const int rem = blockIdx.x % per_b;
    const int ti  = rem / TS, si = rem % TS;
    const int t0  = ti * 128, s0 = si * 64;
    const int b   = b0 + bb;
    float*          logits_c = logc + (size_t)bb * TC * T;
    __hip_bfloat16* li_c     = lic  + (size_t)bb * TC * T;

    const int tid = threadIdx.x, lane = tid & 63, wid = tid >> 6;
    const int wm  = wid >> 1, wn = wid & 1;
    const int fr  = lane & 15, k8 = (lane >> 4) * 8;
    const size_t qb = (size_t)b * T * DK;

    short8 ah[4][2], al[4][2];
#pragma unroll
    for (int mf = 0; mf < 4; ++mf)
#pragma unroll
        for (int ks = 0; ks < 2; ++ks) {
            size_t off = qb + (size_t)(t_off + t0 + wm * 64 + mf * 16 + fr) * DK + ks * 32 + k8;
            ah[mf][ks] = *(const short8*)(qh + off);
            al[mf][ks] = *(const short8*)(ql + off);
        }
    short8 bh[2][2], bl[2][2], bc[2][2];
#pragma unroll
    for (int nf = 0; nf < 2; ++nf)
#pragma unroll
        for (int ks = 0; ks < 2; ++ks) {
            size_t off = (size_t)(s0 + wn * 32 + nf * 16 + fr) * DK + ks * 32 + k8;
            bh[nf][ks] = *(const short8*)(kh + qb + off);
            bl[nf][ks] = *(const short8*)(kl + qb + off);
            bc[nf][ks] = *(const short8*)(copeT + off);
        }

    f32x4 accL[4][2], accM[4][2];
#pragma unroll
    for (int mf = 0; mf < 4; ++mf)
#pragma unroll
        for (int nf = 0; nf < 2; ++nf) {
            accL[mf][nf] = (f32x4){0.f, 0.f, 0.f, 0.f};
            accM[mf][nf] = (f32x4){0.f, 0.f, 0.f, 0.f};
        }

#pragma unroll
    for (int mf = 0; mf < 4; ++mf)
#pragma unroll
        for (int nf = 0; nf < 2; ++nf)
#pragma unroll
            for (int ks = 0; ks < 2; ++ks) {
                accL[mf][nf] = __builtin_amdgcn_mfma_f32_16x16x32_bf16(ah[mf][ks], bh[nf][ks], accL[mf][nf], 0, 0, 0);
                accL[mf][nf] = __builtin_amdgcn_mfma_f32_16x16x32_bf16(ah[mf][ks], bl[nf][ks], accL[mf][nf], 0, 0, 0);
                accL[mf][nf] = __builtin_amdgcn_mfma_f32_16x16x32_bf16(al[mf][ks], bh[nf][ks], accL[mf][nf], 0, 0, 0);
                accM[mf][nf] = __builtin_amdgcn_mfma_f32_16x16x32_bf16(ah[mf][ks], bc[nf][ks], accM[mf][nf], 0, 0, 0);
            }

    const int r4 = (lane >> 4) * 4;
#pragma unroll
    for (int mf = 0; mf < 4; ++mf)
#pragma unroll
        for (int nf = 0; nf < 2; ++nf) {
            const int cg = s0 + wn * 32 + nf * 16 + fr;
#pragma unroll
            for (int j = 0; j < 4; ++j) {
                const int rl = t0 + wm * 64 + mf * 16 + r4 + j;
                const size_t o = (size_t)rl * T + cg;
                logits_c[o] = accL[mf][nf][j];
                li_c[o]     = __float2bfloat16(accM[mf][nf][j]);
            }
        }
}

// ---------------------------------------------------------------------------
// Phase 2: logits -> registers; li -> LDS; wave scan + fixup.
// Writes p as SINGLE bf16 IN PLACE over the li buffer (li dead after read).
// ---------------------------------------------------------------------------
__global__ __launch_bounds__(256) void phase2_kernel(
    const float* __restrict__ logc, __hip_bfloat16* __restrict__ lic,
    int t_off, int TC)
{
    constexpr int CH = T / 256;  // 10
    const int tid  = threadIdx.x;
    const int lane = tid & 63;
    const int wv   = tid >> 6;
    const int bb   = blockIdx.x / TC;
    const int rl   = blockIdx.x % TC;
    const int t    = t_off + rl;

    __shared__ __hip_bfloat16 sli[T];          // 5 KB gather table
    __shared__ float redS[4], redM[4], redE[4];

    const float*    lrow  = logc + ((size_t)bb * TC + rl) * T;
    __hip_bfloat16* lirow = lic  + ((size_t)bb * TC + rl) * T;

    // li -> LDS, dword-coalesced
#pragma unroll
    for (int i = 0; i < 5; ++i) {
        const int idx = i * 256 + tid;
        ((unsigned int*)sli)[idx] = ((const unsigned int*)lirow)[idx];
    }

    // logits -> registers (float2), sigmoid, thread-local sum
    const int s0 = tid * CH;
    float lg[CH], g[CH];
    float lsum = 0.f;
    const float2* lr2 = (const float2*)(lrow + s0);
#pragma unroll
    for (int i = 0; i < 5; ++i) {
        float2 v = lr2[i];
        lg[2 * i] = v.x; lg[2 * i + 1] = v.y;
    }
#pragma unroll
    for (int i = 0; i < CH; ++i) {
        g[i] = 1.0f / (1.0f + __expf(-lg[i]));
        lsum += g[i];
    }

    // wave-inclusive scan of lsum
    float incl = lsum;
#pragma unroll
    for (int off = 1; off < 64; off <<= 1) {
        float n = __shfl_up(incl, off);
        if (lane >= off) incl += n;
    }
    if (lane == 63) redS[wv] = incl;
    __syncthreads();                            // covers sli + redS
    float total = 0.f, wpre = 0.f;
#pragma unroll
    for (int w2 = 0; w2 < 4; ++w2) {
        float tw = redS[w2];
        total += tw;
        if (w2 < wv) wpre += tw;
    }
    float run = wpre + incl - lsum;

    // CoPE bias + causal mask
    float att[CH];
    float lmax = -INFINITY;
#pragma unroll
    for (int i = 0; i < CH; ++i) {
        int s = s0 + i;
        float pos = total - run;
        run += g[i];
        pos = fminf(pos, (float)(T - 1));
        float pf = floorf(pos);
        float w  = pos - pf;
        int ipf  = (int)pf;
        int ipc  = (int)ceilf(pos);
        float bias = __bfloat162float(sli[ipc]) * w
                   + __bfloat162float(sli[ipf]) * (1.0f - w);
        float al = lg[i] * 0.125f + bias;
        if (s > t) al = -INFINITY;
        att[i] = al;
        lmax = fmaxf(lmax, al);
    }

#pragma unroll
    for (int off = 32; off > 0; off >>= 1) lmax = fmaxf(lmax, __shfl_down(lmax, off));
    if (lane == 0) redM[wv] = lmax;
    __syncthreads();
    const float bmax = fmaxf(fmaxf(redM[0], redM[1]), fmaxf(redM[2], redM[3]));

    float e[CH];
    float esum = 0.f;
#pragma unroll
    for (int i = 0; i < CH; ++i) {
        e[i] = __expf(att[i] - bmax);           // exp(-inf)=0 covers mask
        esum += e[i];
    }
#pragma unroll
    for (int off = 32; off > 0; off >>= 1) esum += __shfl_down(esum, off);
    if (lane == 0) redE[wv] = esum;
    __syncthreads();
    const float rden = 1.0f / (redE[0] + redE[1] + redE[2] + redE[3]);

    // p -> bf16, packed dword stores over li (all lanes wrote own row region)
    unsigned int pw[5];
#pragma unroll
    for (int i = 0; i < 5; ++i) {
        __hip_bfloat16 p0 = __float2bfloat16(e[2 * i] * rden);
        __hip_bfloat16 p1 = __float2bfloat16(e[2 * i + 1] * rden);
        pw[i] = (unsigned int)*(unsigned short*)&p0
              | ((unsigned int)*(unsigned short*)&p1 << 16);
    }
    unsigned int* dst = (unsigned int*)(lirow + s0);
#pragma unroll
    for (int i = 0; i < 5; ++i) dst[i] = pw[i];
}

// ---------------------------------------------------------------------------
// GEMM2: out_part = P @ V; P single bf16 (in li buffer); causal skip.
// ---------------------------------------------------------------------------
__global__ __launch_bounds__(256) void gemm2_kernel(
    const __hip_bfloat16* __restrict__ lic, const __hip_bfloat16* __restrict__ vT,
    float* __restrict__ part, int b0, int t_off, int TC)
{
    const int per_b = (TC / 128) * SS;
    const int bb  = blockIdx.x / per_b;
    const int rem = blockIdx.x % per_b;
    const int ti  = rem / SS, sc = rem % SS;
    const int t0  = ti * 128;
    const int sb  = sc * (T / SS);
    if (sb > t_off + t0 + 127) return;          // fully above causal diagonal
    const int b   = b0 + bb;
    const __hip_bfloat16* p_c = lic + (size_t)bb * TC * T;

    const int tid = threadIdx.x, lane = tid & 63, wid = tid >> 6;
    const int wm  = wid >> 1, wn = wid & 1;
    const int fr  = lane & 15, k8 = (lane >> 4) * 8;
    const size_t vb = (size_t)b * DK * T;

    f32x4 acc[4][2];
#pragma unroll
    for (int mf = 0; mf < 4; ++mf)
#pragma unroll
        for (int nf = 0; nf < 2; ++nf) acc[mf][nf] = (f32x4){0.f, 0.f, 0.f, 0.f};

    for (int ks = 0; ks < (T / SS) / 32; ++ks) {   // 10 k-steps
        const int s = sb + ks * 32 + k8;
        short8 a_p[4], bv[2];
#pragma unroll
        for (int mf = 0; mf < 4; ++mf)
            a_p[mf] = *(const short8*)(p_c + (size_t)(t0 + wm * 64 + mf * 16 + fr) * T + s);
#pragma unroll
        for (int nf = 0; nf < 2; ++nf)
            bv[nf] = *(const short8*)(vT + vb + (size_t)(wn * 32 + nf * 16 + fr) * T + s);
#pragma unroll
        for (int mf = 0; mf < 4; ++mf)
#pragma unroll
            for (int nf = 0; nf < 2; ++nf)
                acc[mf][nf] = __builtin_amdgcn_mfma_f32_16x16x32_bf16(a_p[mf], bv[nf], acc[mf][nf], 0, 0, 0);
    }

    const int r4 = (lane >> 4) * 4;
#pragma unroll
    for (int mf = 0; mf < 4; ++mf)
#pragma unroll
        for (int nf = 0; nf < 2; ++nf) {
            const int cg = wn * 32 + nf * 16 + fr;
#pragma unroll
            for (int j = 0; j < 4; ++j) {
                const int rl = t0 + wm * 64 + mf * 16 + r4 + j;
                part[(((size_t)bb * SS + sc) * TC + rl) * DK + cg] = acc[mf][nf][j];
            }
        }
}

__global__ __launch_bounds__(256) void reduce_kernel(
    const float* __restrict__ part, float* __restrict__ out,
    int b0, int t_off, int TC)
{
    const int per_b = (TC * DK) / 256;
    const int bb = blockIdx.x / per_b;
    const int ii = (blockIdx.x % per_b) * 256 + threadIdx.x;  // < TC*DK
    const int rl = ii >> 6, d = ii & 63;
    const int t  = t_off + rl;
    const int sc_max = min(SS - 1, t / (T / SS));
    float s = 0.f;
    for (int sc = 0; sc <= sc_max; ++sc)
        s += part[(((size_t)bb * SS + sc) * TC + rl) * DK + d];
    out[((size_t)(b0 + bb) * T + t) * DK + d] = s;
}

extern "C" void kernel_launch(void* const* d_in, const int* in_sizes, int n_in,
                              void* d_out, int out_size, void* d_ws, size_t ws_size,
                              hipStream_t stream)
{
    const float* x    = (const float*)d_in[0];
    const float* w_q  = (const float*)d_in[1];
    const float* w_k  = (const float*)d_in[2];
    const float* w_v  = (const float*)d_in[3];
    const float* w_qs = (const float*)d_in[4];
    const float* w_ks = (const float*)d_in[5];
    const float* w_vs = (const float*)d_in[6];
    const float* w_qe = (const float*)d_in[7];
    const float* w_ke = (const float*)d_in[8];
    const float* w_ve = (const float*)d_in[9];
    const float* g_m  = (const float*)d_in[10];
    const float* b_m  = (const float*)d_in[11];
    const float* g_s  = (const float*)d_in[12];
    const float* b_s  = (const float*)d_in[13];
    const float* g_e  = (const float*)d_in[14];
    const float* b_e  = (const float*)d_in[15];
    const float* cope = (const float*)d_in[16];

    const size_t n_qk  = (size_t)B_N * T * DK;
    const size_t n_xn  = (size_t)B_N * T * D_IN;
    const size_t n_wt  = (size_t)9 * DK * D_IN;
    const size_t fixedB = 5 * n_qk * 2 + (size_t)T * DK * 2
                        + 2 * n_xn * 2 + 2 * n_wt * 2;
    auto chunkB = [&](size_t TC) -> size_t {
        return TC * (size_t)T * 4          // logits (f32)
             + TC * (size_t)T * 2          // li -> p (bf16, in place)
             + (size_t)SS * TC * DK * 4;   // part
    };
    int TC, NB;
    if (fixedB + 2 * chunkB(T) <= ws_size)       { TC = T;    NB = 2; }
    else if (fixedB + chunkB(T) <= ws_size)      { TC = T;    NB = 1; }
    else if (fixedB + chunkB(1280) <= ws_size)   { TC = 1280; NB = 1; }
    else                                         { TC = 640;  NB = 1; }

    char* w = (char*)d_ws;
    __hip_bfloat16* qh    = (__hip_bfloat16*)w; w += n_qk * 2;
    __hip_bfloat16* ql    = (__hip_bfloat16*)w; w += n_qk * 2;
    __hip_bfloat16* kh    = (__hip_bfloat16*)w; w += n_qk * 2;
    __hip_bfloat16* kl    = (__hip_bfloat16*)w; w += n_qk * 2;
    __hip_bfloat16* vT    = (__hip_bfloat16*)w; w += n_qk * 2;
    __hip_bfloat16* copeT = (__hip_bfloat16*)w; w += (size_t)T * DK * 2;
    __hip_bfloat16* xnh   = (__hip_bfloat16*)w; w += n_xn * 2;
    __hip_bfloat16* xnl   = (__hip_bfloat16*)w; w += n_xn * 2;
    __hip_bfloat16* wth   = (__hip_bfloat16*)w; w += n_wt * 2;
    __hip_bfloat16* wtl   = (__hip_bfloat16*)w; w += n_wt * 2;
    float*          logc  = (float*)w;          w += (size_t)NB * TC * T * 4;
    __hip_bfloat16* lic   = (__hip_bfloat16*)w; w += (size_t)NB * TC * T * 2;
    float*          part  = (float*)w;

    constexpr int LN_BLOCKS   = (B_N * T) / 4;
    const int     PREP_BLOCKS = (int)((n_wt + (size_t)T * DK + 255) / 256);
    lnprep_kernel<<<LN_BLOCKS + PREP_BLOCKS, 256, 0, stream>>>(
        x, g_m, b_m, g_s, b_s, g_e, b_e,
        w_qs, w_ks, w_vs, w_q, w_k, w_v, w_qe, w_ke, w_ve, cope,
        xnh, xnl, wth, wtl, copeT);

    qkv_gemm_kernel<<<(B_N * T / 64) * 3, 256, 0, stream>>>(
        xnh, xnl, wth, wtl, qh, ql, kh, kl, vT);

    for (int b0 = 0; b0 < B_N; b0 += NB)
        for (int t_off = 0; t_off < T; t_off += TC) {
            gemm1_kernel<<<NB * (TC / 128) * (T / 64), 256, 0, stream>>>(
                qh, ql, kh, kl, copeT, logc, lic, b0, t_off, TC);
            phase2_kernel<<<NB * TC, 256, 0, stream>>>(
                logc, lic, t_off, TC);
            gemm2_kernel<<<NB * (TC / 128) * SS, 256, 0, stream>>>(
                lic, vT, part, b0, t_off, TC);
            reduce_kernel<<<NB * (TC * DK) / 256, 256, 0, stream>>>(
                part, (float*)d_out, b0, t_off, TC);
        }
}